// Round 11
// baseline (258.748 us; speedup 1.0000x reference)
//
#include <hip/hip_runtime.h>
#include <math.h>

#define NN 10000
#define EE 320000
#define TE 32
#define TN 16
#define INV_AVG (1.0f / 565.0f)

// out layout (flat concat): positions[120000] | vectors[120000] | features[1280000] | skip[120000]
#define OUT_POS 0
#define OUT_VEC 120000
#define OUT_FEAT 240000
#define OUT_SKIP 1520000
#define OUT_TOTAL 1640000

// ws layout: bf16 weight fragments (ushort units), then byte-offset regions
#define WS_WE0 0                       // [9][8][64][8] = 36864 (K 264->288; k=264 row = be0)
#define WS_WE1 36864
#define WS_WX0 53248
#define WS_WX1 69632
#define WS_WY0 86016
#define WS_WY1 102400
#define WS_WH0 118784                  // [8][8][64][8] = 32768 (K=256)
#define WS_WH1 151552
#define WS_WH2 167936
#define WS_WXF 184320                  // [4][64][8] = 2048 (head, M=4 padded 16)
#define WS_WYF 186368                  // end 188416 ushorts = 376832 bytes
#define WS_OFF_NF 376832               // nf_bf [10000][128] = 2,560,000 B
#define WS_OFF_SORT 2936832            // int[EE]
#define WS_OFF_CNT  4216832            // int[NN]
#define WS_OFF_CUR  4256832            // int[NN]

typedef __attribute__((ext_vector_type(8))) short bfrag;
typedef __attribute__((ext_vector_type(4))) float f4acc;

__device__ __forceinline__ float siluf(float x) {
    return x * __builtin_amdgcn_rcpf(1.0f + __expf(-x));
}
__device__ __forceinline__ float tanh_fast(float x) {
    return 1.0f - 2.0f * __builtin_amdgcn_rcpf(__expf(2.0f * x) + 1.0f);
}
__device__ __forceinline__ float sigmoid_fast(float x) {
    return __builtin_amdgcn_rcpf(1.0f + __expf(-x));
}
__device__ __forceinline__ unsigned int cvt_pk_bf16(float lo, float hi) {
    unsigned int r;
    asm("v_cvt_pk_bf16_f32 %0, %1, %2" : "=v"(r) : "v"(lo), "v"(hi));
    return r;
}
__device__ __forceinline__ unsigned short f2bf(float x) {
    union { float f; unsigned int u; } c; c.f = x;
    unsigned int r = c.u + 0x7FFFu + ((c.u >> 16) & 1u);
    return (unsigned short)(r >> 16);
}
__device__ __forceinline__ float bf2f(unsigned short h) {
    union { unsigned int u; float f; } c; c.u = ((unsigned int)h) << 16; return c.f;
}

__global__ __launch_bounds__(256) void init_kernel(const float* __restrict__ pos,
                                                   float* __restrict__ out,
                                                   int* __restrict__ cnt)
{
    int idx = blockIdx.x * 256 + threadIdx.x;
    if (idx < OUT_TOTAL) out[idx] = (idx < 120000) ? pos[idx] : 0.0f;
    if (idx < NN) cnt[idx] = 0;
}

// ---------------- fused prep: nf->bf16, receiver hist, weight fragments ----------------
__global__ __launch_bounds__(256) void prep_all(
    const float* __restrict__ nf, unsigned short* __restrict__ nfb,
    const int* __restrict__ rcv, int* __restrict__ cnt,
    const float* __restrict__ We0, const float* __restrict__ be0,
    const float* __restrict__ We1,
    const float* __restrict__ Wx0, const float* __restrict__ Wx1,
    const float* __restrict__ Wy0, const float* __restrict__ Wy1,
    const float* __restrict__ Wh0, const float* __restrict__ Wh1,
    const float* __restrict__ Wh2,
    const float* __restrict__ Wxf, const float* __restrict__ Wyf,
    unsigned short* __restrict__ wsW)
{
    int tid = blockIdx.x * 256 + threadIdx.x;
    // nf conversion
    int i = tid * 8;
    if (i < NN * 128) {
        float4 a = *(const float4*)(nf + i);
        float4 b = *(const float4*)(nf + i + 4);
        uint4 pk;
        pk.x = cvt_pk_bf16(a.x, a.y);
        pk.y = cvt_pk_bf16(a.z, a.w);
        pk.z = cvt_pk_bf16(b.x, b.y);
        pk.w = cvt_pk_bf16(b.z, b.w);
        *(uint4*)(nfb + i) = pk;
    }
    // receiver histogram (cnt zeroed by init_kernel, stream-ordered)
    int e = tid * 2;
    if (e < EE) {
        atomicAdd(cnt + rcv[e], 1);
        atomicAdd(cnt + rcv[e + 1], 1);
    }
    // weight fragments
    if (tid >= 23552) return;
    if (tid >= 23040) {
        const float* Wf = (tid < 23296) ? Wxf : Wyf;
        unsigned short* dst = wsW + ((tid < 23296) ? WS_WXF : WS_WYF);
        int rel = tid - ((tid < 23296) ? 23040 : 23296);
        int kc = rel >> 6, lane = rel & 63;
        int lhi = lane >> 4, llo = lane & 15;
        unsigned short* o = dst + ((kc * 64 + lane) << 3);
#pragma unroll
        for (int j = 0; j < 8; ++j) {
            int k = kc * 32 + lhi * 8 + j;
            o[j] = (llo < 4) ? f2bf(Wf[k * 4 + llo]) : (unsigned short)0;
        }
        return;
    }
    const float* W; unsigned short* dst; int Kact = 128, rel; int isWe0 = 0;
    if (tid < 4608)        { W = We0; dst = wsW + WS_WE0; Kact = 264; rel = tid; isWe0 = 1; }
    else if (tid < 14848)  {
        int r = tid - 4608; int m = r >> 11; rel = r & 2047;
        switch (m) {
            case 0: W = We1; dst = wsW + WS_WE1; break;
            case 1: W = Wx0; dst = wsW + WS_WX0; break;
            case 2: W = Wx1; dst = wsW + WS_WX1; break;
            case 3: W = Wy0; dst = wsW + WS_WY0; break;
            default: W = Wy1; dst = wsW + WS_WY1; break;
        }
    }
    else if (tid < 18944)  { W = Wh0; dst = wsW + WS_WH0; Kact = 256; rel = tid - 14848; }
    else if (tid < 20992)  { W = Wh1; dst = wsW + WS_WH1; rel = tid - 18944; }
    else                   { W = Wh2; dst = wsW + WS_WH2; rel = tid - 20992; }
    int lane = rel & 63, oc = (rel >> 6) & 7, kc = rel >> 9;
    int k0 = kc * 32 + ((lane >> 4) << 3);
    int col = oc * 16 + (lane & 15);
    unsigned short* o = dst + (((kc * 8 + oc) * 64 + lane) << 3);
#pragma unroll
    for (int j = 0; j < 8; ++j) {
        int k = k0 + j;
        unsigned short v = 0;
        if (k < Kact) v = f2bf(W[k * 128 + col]);
        else if (isWe0 && k == 264) v = f2bf(be0[col]);   // bias folded at k=264 (ef col = 1)
        o[j] = v;
    }
}

// two-level scan: 1024 threads, wave shuffle scan + wave-sum scan
__global__ __launch_bounds__(1024) void scan_kernel(const int* __restrict__ cnt,
                                                    int* __restrict__ cursor)
{
    __shared__ int wsum[16];
    int t = threadIdx.x;
    int lane = t & 63, wid = t >> 6;
    int base = t * 10;
    int c[10];
    int s = 0;
#pragma unroll
    for (int i = 0; i < 10; ++i) {
        int b = base + i;
        c[i] = (b < NN) ? cnt[b] : 0;
        s += c[i];
    }
    int run = s;
#pragma unroll
    for (int off = 1; off < 64; off <<= 1) {
        int v = __shfl_up(run, off);
        if (lane >= off) run += v;
    }
    if (lane == 63) wsum[wid] = run;
    __syncthreads();
    if (t < 16) {
        int v = wsum[t];
#pragma unroll
        for (int off = 1; off < 16; off <<= 1) {
            int u = __shfl_up(v, off);
            if (t >= off) v += u;
        }
        wsum[t] = v;   // inclusive wave sums
    }
    __syncthreads();
    int wave_excl = (wid == 0) ? 0 : wsum[wid - 1];
    int excl = wave_excl + run - s;
#pragma unroll
    for (int i = 0; i < 10; ++i) {
        int b = base + i;
        if (b < NN) { cursor[b] = excl; excl += c[i]; }
    }
}

__global__ __launch_bounds__(256) void scatter_sort_kernel(const int* __restrict__ rcv,
                                                           int* __restrict__ cursor,
                                                           int* __restrict__ sortedIdx)
{
    int e = blockIdx.x * 256 + threadIdx.x;
    if (e < EE) {
        int slot = atomicAdd(cursor + rcv[e], 1);
        sortedIdx[slot] = e;
    }
}

// generic GEMM core: acc[MT][NT] += W-frag (A) x LDS activations (B)
template<int KC, int MT, int NT>
__device__ __forceinline__ void gemm_lds(const unsigned short* __restrict__ fragW,
                                         const unsigned short* Bld, const int bstride,
                                         const int tile0, const int lane,
                                         f4acc acc[MT][NT])
{
    const int lhi = lane >> 4, llo = lane & 15;
#pragma unroll
    for (int kc = 0; kc < KC; ++kc) {
        bfrag b[NT];
#pragma unroll
        for (int nt = 0; nt < NT; ++nt)
            b[nt] = *(const bfrag*)(Bld + (nt * 16 + llo) * bstride + kc * 32 + lhi * 8);
#pragma unroll
        for (int i = 0; i < MT; ++i) {
            bfrag a = *(const bfrag*)(fragW + (((kc * 8 + tile0 + i) * 64 + lane) << 3));
#pragma unroll
            for (int nt = 0; nt < NT; ++nt)
                acc[i][nt] = __builtin_amdgcn_mfma_f32_16x16x32_bf16(a, b[nt], acc[i][nt], 0, 0, 0);
        }
    }
}

template<int NT>
__device__ __forceinline__ void epilogue_silu_t(f4acc acc[2][NT], const float* __restrict__ bias,
                                                unsigned short* Dld, int lane, int w)
{
    const int lhi = lane >> 4, llo = lane & 15;
#pragma unroll
    for (int i = 0; i < 2; ++i) {
        int ch = (w * 2 + i) * 16 + lhi * 4;
        float4 bv = *(const float4*)(bias + ch);
#pragma unroll
        for (int nt = 0; nt < NT; ++nt) {
            uint2 pk;
            pk.x = cvt_pk_bf16(siluf(acc[i][nt][0] + bv.x), siluf(acc[i][nt][1] + bv.y));
            pk.y = cvt_pk_bf16(siluf(acc[i][nt][2] + bv.z), siluf(acc[i][nt][3] + bv.w));
            *(uint2*)(Dld + (nt * 16 + llo) * 136 + ch) = pk;
        }
    }
}

__device__ __forceinline__ void epilogue_silu_nobias(f4acc acc[2][2],
                                                     unsigned short* Dld, int lane, int w)
{
    const int lhi = lane >> 4, llo = lane & 15;
#pragma unroll
    for (int i = 0; i < 2; ++i) {
        int ch = (w * 2 + i) * 16 + lhi * 4;
#pragma unroll
        for (int nt = 0; nt < 2; ++nt) {
            uint2 pk;
            pk.x = cvt_pk_bf16(siluf(acc[i][nt][0]), siluf(acc[i][nt][1]));
            pk.y = cvt_pk_bf16(siluf(acc[i][nt][2]), siluf(acc[i][nt][3]));
            *(uint2*)(Dld + (nt * 16 + llo) * 136 + ch) = pk;
        }
    }
}

__global__ __launch_bounds__(256, 4) void edge_kernel(
    const float* __restrict__ pos, const float* __restrict__ vec,
    const unsigned short* __restrict__ nfb,
    const int* __restrict__ snd, const int* __restrict__ rcv,
    const int* __restrict__ sortedIdx,
    const unsigned short* __restrict__ wsW,
    const float* __restrict__ be1,
    const float* __restrict__ Winf, const float* __restrict__ binf,
    const float* __restrict__ bx0, const float* __restrict__ bx1,
    const float* __restrict__ by0, const float* __restrict__ by1,
    float* outPos, float* outSkip, float* outFeat)
{
    __shared__ unsigned short L2T[TE * 40];
    __shared__ unsigned short H0[TE * 136];   // h0, then h1 per branch
    __shared__ unsigned short Hm[TE * 136];   // m
    __shared__ unsigned short H2[TE * 136];   // h2 per branch
    __shared__ float dstore[TE * 24];
    __shared__ float pxy[TE * 8];
    __shared__ float gateacc[TE];
    __shared__ int sidx[TE], ridx[TE];

    const int t = threadIdx.x;
    const int lane = t & 63, w = t >> 6;
    const int lhi = lane >> 4, llo = lane & 15;
    const int e_base = blockIdx.x * TE;

    // ---- phase A ----
    if (t < TE) {
        int eid = sortedIdx[e_base + t];
        int sn = snd[eid], rn = rcv[eid];
        sidx[t] = sn; ridx[t] = rn;   // ridx non-decreasing within block
#pragma unroll
        for (int tensor = 0; tensor < 2; ++tensor) {
            const float* c = tensor ? vec : pos;
#pragma unroll
            for (int v = 0; v < 4; ++v) {
                float d0 = c[rn * 12 + v * 3 + 0] - c[sn * 12 + v * 3 + 0];
                float d1 = c[rn * 12 + v * 3 + 1] - c[sn * 12 + v * 3 + 1];
                float d2 = c[rn * 12 + v * 3 + 2] - c[sn * 12 + v * 3 + 2];
                float ss = fmaf(d0, d0, fmaf(d1, d1, d2 * d2)) + 1e-8f;
                float l = sqrtf(ss);
                float inv = __builtin_amdgcn_rcpf(1.0f + l);
                L2T[t * 40 + tensor * 4 + v] = f2bf(ss);
                dstore[t * 24 + tensor * 12 + v * 3 + 0] = d0 * inv;
                dstore[t * 24 + tensor * 12 + v * 3 + 1] = d1 * inv;
                dstore[t * 24 + tensor * 12 + v * 3 + 2] = d2 * inv;
            }
        }
#pragma unroll
        for (int j = 0; j < 6; ++j)
            *(uint2*)(L2T + t * 40 + 8 + j * 4) = make_uint2(0u, 0u);
        L2T[t * 40 + 8] = 0x3F80u;    // ef col k=264 = 1.0 (bias column, pairs with be0 row)
    }
    if (t >= 64 && t < 96) gateacc[t - 64] = 0.0f;
    __syncthreads();   // B1

    // ---- phase B: h0 = silu(ef @ We0') (bias folded into k=264) ----
    {
        const int sn0 = sidx[llo], sn1 = sidx[16 + llo];
        const int rn0 = ridx[llo], rn1 = ridx[16 + llo];
        const unsigned short* s0 = nfb + sn0 * 128 + lhi * 8;
        const unsigned short* s1 = nfb + sn1 * 128 + lhi * 8;
        const unsigned short* r0 = nfb + rn0 * 128 + lhi * 8;
        const unsigned short* r1 = nfb + rn1 * 128 + lhi * 8;
        const int mt0 = w * 2;
        f4acc acc[2][2];
#pragma unroll
        for (int i = 0; i < 2; ++i) { acc[i][0] = (f4acc){0.f,0.f,0.f,0.f}; acc[i][1] = (f4acc){0.f,0.f,0.f,0.f}; }
#pragma unroll
        for (int kc = 0; kc < 8; ++kc) {
            bfrag b0 = *(const bfrag*)((kc < 4 ? s0 : r0) + (kc & 3) * 32);
            bfrag b1 = *(const bfrag*)((kc < 4 ? s1 : r1) + (kc & 3) * 32);
#pragma unroll
            for (int i = 0; i < 2; ++i) {
                bfrag a = *(const bfrag*)(wsW + WS_WE0 + (((kc * 8 + mt0 + i) * 64 + lane) << 3));
                acc[i][0] = __builtin_amdgcn_mfma_f32_16x16x32_bf16(a, b0, acc[i][0], 0, 0, 0);
                acc[i][1] = __builtin_amdgcn_mfma_f32_16x16x32_bf16(a, b1, acc[i][1], 0, 0, 0);
            }
        }
        {
            bfrag b0 = *(const bfrag*)(L2T + llo * 40 + lhi * 8);
            bfrag b1 = *(const bfrag*)(L2T + (16 + llo) * 40 + lhi * 8);
#pragma unroll
            for (int i = 0; i < 2; ++i) {
                bfrag a = *(const bfrag*)(wsW + WS_WE0 + (((8 * 8 + mt0 + i) * 64 + lane) << 3));
                acc[i][0] = __builtin_amdgcn_mfma_f32_16x16x32_bf16(a, b0, acc[i][0], 0, 0, 0);
                acc[i][1] = __builtin_amdgcn_mfma_f32_16x16x32_bf16(a, b1, acc[i][1], 0, 0, 0);
            }
        }
        epilogue_silu_nobias(acc, H0, lane, w);
    }
    __syncthreads();   // B2

    // ---- phase C: m + gate fused ----
    {
        f4acc acc[2][2];
#pragma unroll
        for (int i = 0; i < 2; ++i) { acc[i][0] = (f4acc){0.f,0.f,0.f,0.f}; acc[i][1] = (f4acc){0.f,0.f,0.f,0.f}; }
        gemm_lds<4, 2, 2>(wsW + WS_WE1, H0, 136, w * 2, lane, acc);
        float gp0 = 0.0f, gp1 = 0.0f;
#pragma unroll
        for (int i = 0; i < 2; ++i) {
            int ch = (w * 2 + i) * 16 + lhi * 4;
            float4 bv = *(const float4*)(be1 + ch);
            float4 wg = *(const float4*)(Winf + ch);
#pragma unroll
            for (int nt = 0; nt < 2; ++nt) {
                float v0 = siluf(acc[i][nt][0] + bv.x);
                float v1 = siluf(acc[i][nt][1] + bv.y);
                float v2 = siluf(acc[i][nt][2] + bv.z);
                float v3 = siluf(acc[i][nt][3] + bv.w);
                uint2 pk;
                pk.x = cvt_pk_bf16(v0, v1);
                pk.y = cvt_pk_bf16(v2, v3);
                *(uint2*)(Hm + (nt * 16 + llo) * 136 + ch) = pk;
                float g = fmaf(v0, wg.x, fmaf(v1, wg.y, fmaf(v2, wg.z, v3 * wg.w)));
                if (nt == 0) gp0 += g; else gp1 += g;
            }
        }
        gp0 += __shfl_xor(gp0, 16); gp0 += __shfl_xor(gp0, 32);
        gp1 += __shfl_xor(gp1, 16); gp1 += __shfl_xor(gp1, 32);
        if (lane < 16) {
            atomicAdd(&gateacc[lane], gp0);
            atomicAdd(&gateacc[16 + lane], gp1);
        }
    }
    __syncthreads();   // B3

    // ---- D-x: h1x = silu(m @ Wx0 + bx0) -> H0 ----
    {
        f4acc acc[2][2];
#pragma unroll
        for (int i = 0; i < 2; ++i) { acc[i][0] = (f4acc){0.f,0.f,0.f,0.f}; acc[i][1] = (f4acc){0.f,0.f,0.f,0.f}; }
        gemm_lds<4, 2, 2>(wsW + WS_WX0, Hm, 136, w * 2, lane, acc);
        epilogue_silu_t<2>(acc, bx0, H0, lane, w);
    }
    __syncthreads();   // B4

    // ---- E-x: h2x = silu(h1x @ Wx1 + bx1) -> H2 ----
    {
        f4acc acc[2][2];
#pragma unroll
        for (int i = 0; i < 2; ++i) { acc[i][0] = (f4acc){0.f,0.f,0.f,0.f}; acc[i][1] = (f4acc){0.f,0.f,0.f,0.f}; }
        gemm_lds<4, 2, 2>(wsW + WS_WX1, H0, 136, w * 2, lane, acc);
        epilogue_silu_t<2>(acc, bx1, H2, lane, w);
    }
    __syncthreads();   // B5

    // ---- D-y (all waves, Hm -> H0) overlapped with head-x (waves 0-1, H2 -> pxy) ----
    {
        f4acc acc[2][2];
#pragma unroll
        for (int i = 0; i < 2; ++i) { acc[i][0] = (f4acc){0.f,0.f,0.f,0.f}; acc[i][1] = (f4acc){0.f,0.f,0.f,0.f}; }
        gemm_lds<4, 2, 2>(wsW + WS_WY0, Hm, 136, w * 2, lane, acc);
        epilogue_silu_t<2>(acc, by0, H0, lane, w);
        if (w < 2) {
            f4acc h = (f4acc){0.f, 0.f, 0.f, 0.f};
#pragma unroll
            for (int kc = 0; kc < 4; ++kc) {
                bfrag b = *(const bfrag*)(H2 + (w * 16 + llo) * 136 + kc * 32 + lhi * 8);
                bfrag a = *(const bfrag*)(wsW + WS_WXF + ((kc * 64 + lane) << 3));
                h = __builtin_amdgcn_mfma_f32_16x16x32_bf16(a, b, h, 0, 0, 0);
            }
            if (lhi == 0) {
#pragma unroll
                for (int v = 0; v < 4; ++v)
                    pxy[(w * 16 + llo) * 8 + v] = h[v];
            }
        }
    }
    __syncthreads();   // B6

    // ---- E-y: h2y = silu(h1y @ Wy1 + by1) -> H2 ----
    {
        f4acc acc[2][2];
#pragma unroll
        for (int i = 0; i < 2; ++i) { acc[i][0] = (f4acc){0.f,0.f,0.f,0.f}; acc[i][1] = (f4acc){0.f,0.f,0.f,0.f}; }
        gemm_lds<4, 2, 2>(wsW + WS_WY1, H0, 136, w * 2, lane, acc);
        epilogue_silu_t<2>(acc, by1, H2, lane, w);
    }
    __syncthreads();   // B7

    // ---- head-y (waves 0-1) ----
    if (w < 2) {
        f4acc h = (f4acc){0.f, 0.f, 0.f, 0.f};
#pragma unroll
        for (int kc = 0; kc < 4; ++kc) {
            bfrag b = *(const bfrag*)(H2 + (w * 16 + llo) * 136 + kc * 32 + lhi * 8);
            bfrag a = *(const bfrag*)(wsW + WS_WYF + ((kc * 64 + lane) << 3));
            h = __builtin_amdgcn_mfma_f32_16x16x32_bf16(a, b, h, 0, 0, 0);
        }
        if (lhi == 0) {
#pragma unroll
            for (int v = 0; v < 4; ++v)
                pxy[(w * 16 + llo) * 8 + 4 + v] = h[v];
        }
    }
    __syncthreads();   // B8

    // ---- finalize heads + gate ----
    pxy[t] = tanh_fast(pxy[t]) * INV_AVG;
    if (t < TE) gateacc[t] = sigmoid_fast(gateacc[t] + binf[0]) * INV_AVG;
    __syncthreads();   // B9

    // ---- merged scatter (sorted receivers) ----
    // features: waves 0-1, 2 halves x 64 channel-pairs; 16-edge runs
    if (t < 128) {
        int half = t >> 6, pair = t & 63;
        int jj = pair * 2;
        int e0h = half * 16;
        float a0 = 0.0f, a1 = 0.0f;
        int prev_r = ridx[e0h];
#pragma unroll
        for (int i = 0; i < 16; ++i) {
            int e = e0h + i;
            int r = ridx[e];
            if (r != prev_r) {
                atomicAdd(outFeat + prev_r * 128 + jj, a0);
                atomicAdd(outFeat + prev_r * 128 + jj + 1, a1);
                a0 = a1 = 0.0f;
                prev_r = r;
            }
            unsigned int pk = *(const unsigned int*)(Hm + e * 136 + jj);
            float g = gateacc[e];
            a0 = fmaf(bf2f((unsigned short)(pk & 0xffffu)), g, a0);
            a1 = fmaf(bf2f((unsigned short)(pk >> 16)), g, a1);
        }
        atomicAdd(outFeat + prev_r * 128 + jj, a0);
        atomicAdd(outFeat + prev_r * 128 + jj + 1, a1);
    } else if (t >= 208) {
        // shifts: wave 3 upper half, 24 comps x 2 halves
        int s = t - 208;
        int c = s >> 1, half = s & 1;
        int tensor = (c >= 12) ? 1 : 0;
        int rem = c - tensor * 12;
        int v = rem / 3;
        float* dstp = tensor ? outSkip : outPos;
        int e0h = half * 16;
        float acc = 0.0f;
        int prev_r = ridx[e0h];
#pragma unroll
        for (int i = 0; i < 16; ++i) {
            int e = e0h + i;
            int r = ridx[e];
            if (r != prev_r) {
                atomicAdd(dstp + prev_r * 12 + rem, acc);
                acc = 0.0f;
                prev_r = r;
            }
            acc = fmaf(dstore[e * 24 + c], pxy[e * 8 + tensor * 4 + v], acc);
        }
        atomicAdd(dstp + prev_r * 12 + rem, acc);
    }
}

// ---------------- node kernel: MFMA phi_h, 16 nodes/block ----------------
__global__ __launch_bounds__(256) void node_kernel(
    const float* __restrict__ nf, const unsigned short* __restrict__ nfb,
    const float* __restrict__ nvec,
    const unsigned short* __restrict__ wsW,
    const float* __restrict__ bh0, const float* __restrict__ bh1,
    const float* __restrict__ bh2,
    float* outFeat /* holds m_i on entry */, float* outVec,
    const float* __restrict__ outSkip)
{
    __shared__ unsigned short A[TN * 264];   // hin bf16 [16][256] stride 264
    __shared__ unsigned short H1[TN * 136];
    __shared__ unsigned short H2b[TN * 136];
    const int t = threadIdx.x;
    const int lane = t & 63, w = t >> 6;
    const int lhi = lane >> 4, llo = lane & 15;
    const int n_base = blockIdx.x * TN;

    // gather m_i (fp32 -> bf16): 16 rows x 64 channel-pairs = 1024 tasks
#pragma unroll
    for (int it = 0; it < 4; ++it) {
        int idx = t + it * 256;
        int row = idx >> 6, q = idx & 63;
        int n = n_base + row;
        float2 v = make_float2(0.f, 0.f);
        if (n < NN) v = *(const float2*)(outFeat + n * 128 + q * 2);
        *(unsigned int*)(A + row * 264 + q * 2) = cvt_pk_bf16(v.x, v.y);
    }
    // copy nf (already bf16 in nfb): 16 rows x 16 b128 = 256 tasks
    {
        int row = t >> 4, q = t & 15;
        int n = n_base + row;
        uint4 v = make_uint4(0u, 0u, 0u, 0u);
        if (n < NN) v = *(const uint4*)(nfb + n * 128 + q * 8);
        *(uint4*)(A + row * 264 + 128 + q * 8) = v;
    }
    __syncthreads();
    {   // L1: h1 = silu(hin @ Wh0 + bh0), K=256
        f4acc acc[2][1];
        acc[0][0] = (f4acc){0.f,0.f,0.f,0.f}; acc[1][0] = (f4acc){0.f,0.f,0.f,0.f};
        gemm_lds<8, 2, 1>(wsW + WS_WH0, A, 264, w * 2, lane, acc);
        epilogue_silu_t<1>(acc, bh0, H1, lane, w);
    }
    __syncthreads();
    {   // L2
        f4acc acc[2][1];
        acc[0][0] = (f4acc){0.f,0.f,0.f,0.f}; acc[1][0] = (f4acc){0.f,0.f,0.f,0.f};
        gemm_lds<4, 2, 1>(wsW + WS_WH1, H1, 136, w * 2, lane, acc);
        epilogue_silu_t<1>(acc, bh1, H2b, lane, w);
    }
    __syncthreads();
    {   // L3: out = h2 @ Wh2 + bh2 + nf (residual), fp32 global store
        f4acc acc[2][1];
        acc[0][0] = (f4acc){0.f,0.f,0.f,0.f}; acc[1][0] = (f4acc){0.f,0.f,0.f,0.f};
        gemm_lds<4, 2, 1>(wsW + WS_WH2, H2b, 136, w * 2, lane, acc);
#pragma unroll
        for (int i = 0; i < 2; ++i) {
            int ch = (w * 2 + i) * 16 + lhi * 4;
            float4 bv = *(const float4*)(bh2 + ch);
            int n = n_base + llo;
            if (n < NN) {
                float4 r = *(const float4*)(nf + n * 128 + ch);
                float4 o;
                o.x = acc[i][0][0] + bv.x + r.x;
                o.y = acc[i][0][1] + bv.y + r.y;
                o.z = acc[i][0][2] + bv.z + r.z;
                o.w = acc[i][0][3] + bv.w + r.w;
                *(float4*)(outFeat + n * 128 + ch) = o;
            }
        }
    }
    // vectors_out = skip + node_vectors : 16 nodes x 12 = 192
    if (t < TN * 12) {
        int n = n_base + t / 12;
        if (n < NN) {
            int g = n_base * 12 + t;
            outVec[g] = outSkip[g] + nvec[g];
        }
    }
}

extern "C" void kernel_launch(void* const* d_in, const int* in_sizes, int n_in,
                              void* d_out, int out_size, void* d_ws, size_t ws_size,
                              hipStream_t stream)
{
    (void)in_sizes; (void)n_in; (void)out_size; (void)ws_size;

    const float* pos  = (const float*)d_in[0];
    const float* vecv = (const float*)d_in[1];
    const float* nf   = (const float*)d_in[2];
    const int*   snd  = (const int*)d_in[3];
    const int*   rcv  = (const int*)d_in[4];
    const float* We0  = (const float*)d_in[5];
    const float* be0  = (const float*)d_in[6];
    const float* We1  = (const float*)d_in[7];
    const float* be1  = (const float*)d_in[8];
    const float* Winf = (const float*)d_in[9];
    const float* binf = (const float*)d_in[10];
    const float* Wx0  = (const float*)d_in[11];
    const float* bx0  = (const float*)d_in[12];
    const float* Wx1  = (const float*)d_in[13];
    const float* bx1  = (const float*)d_in[14];
    const float* Wxf  = (const float*)d_in[15];
    const float* Wy0  = (const float*)d_in[16];
    const float* by0  = (const float*)d_in[17];
    const float* Wy1  = (const float*)d_in[18];
    const float* by1  = (const float*)d_in[19];
    const float* Wyf  = (const float*)d_in[20];
    const float* Wh0  = (const float*)d_in[21];
    const float* bh0  = (const float*)d_in[22];
    const float* Wh1  = (const float*)d_in[23];
    const float* bh1  = (const float*)d_in[24];
    const float* Wh2  = (const float*)d_in[25];
    const float* bh2  = (const float*)d_in[26];

    float* out     = (float*)d_out;
    float* outPos  = out + OUT_POS;
    float* outVec  = out + OUT_VEC;
    float* outFeat = out + OUT_FEAT;
    float* outSkip = out + OUT_SKIP;

    char* ws = (char*)d_ws;
    unsigned short* wsW = (unsigned short*)ws;
    unsigned short* nfb = (unsigned short*)(ws + WS_OFF_NF);
    int* sortedIdx      = (int*)(ws + WS_OFF_SORT);
    int* cnt            = (int*)(ws + WS_OFF_CNT);
    int* cursor         = (int*)(ws + WS_OFF_CUR);

    init_kernel<<<(OUT_TOTAL + 255) / 256, 256, 0, stream>>>(pos, out, cnt);

    prep_all<<<(NN * 128 / 8 + 255) / 256, 256, 0, stream>>>(
        nf, nfb, rcv, cnt,
        We0, be0, We1, Wx0, Wx1, Wy0, Wy1, Wh0, Wh1, Wh2, Wxf, Wyf, wsW);

    scan_kernel<<<1, 1024, 0, stream>>>(cnt, cursor);
    scatter_sort_kernel<<<(EE + 255) / 256, 256, 0, stream>>>(rcv, cursor, sortedIdx);

    edge_kernel<<<EE / TE, 256, 0, stream>>>(
        pos, vecv, nfb, snd, rcv, sortedIdx, wsW,
        be1, Winf, binf,
        bx0, bx1, by0, by1,
        outPos, outSkip, outFeat);

    node_kernel<<<(NN + TN - 1) / TN, 256, 0, stream>>>(
        nf, nfb, vecv, wsW, bh0, bh1, bh2,
        outFeat, outVec, outSkip);
}

// Round 12
// 234.174 us; speedup vs baseline: 1.1049x; 1.1049x over previous
//
#include <hip/hip_runtime.h>
#include <math.h>

#define NN 10000
#define EE 320000
#define TE 32
#define TN 16
#define INV_AVG (1.0f / 565.0f)

// out layout (flat concat): positions[120000] | vectors[120000] | features[1280000] | skip[120000]
#define OUT_POS 0
#define OUT_VEC 120000
#define OUT_FEAT 240000
#define OUT_SKIP 1520000
#define OUT_TOTAL 1640000

// ws layout: bf16 weight fragments (ushort units), then byte-offset regions
#define WS_WE0 0                       // [9][8][64][8] = 36864 (K 264->288; k=264 row = be0)
#define WS_WE1 36864
#define WS_WX0 53248
#define WS_WX1 69632
#define WS_WY0 86016
#define WS_WY1 102400
#define WS_WH0 118784                  // [8][8][64][8] = 32768 (K=256)
#define WS_WH1 151552
#define WS_WH2 167936
#define WS_WXF 184320                  // [4][64][8] = 2048 (head, M=4 padded 16)
#define WS_WYF 186368                  // end 188416 ushorts = 376832 bytes
#define WS_OFF_NF 376832               // nf_bf [10000][128] = 2,560,000 B
#define WS_OFF_SORT 2936832            // int[EE]
#define WS_OFF_CNT  4216832            // int[NN]
#define WS_OFF_CUR  4256832            // int[NN]

typedef __attribute__((ext_vector_type(8))) short bfrag;
typedef __attribute__((ext_vector_type(4))) float f4acc;

__device__ __forceinline__ float siluf(float x) {
    return x * __builtin_amdgcn_rcpf(1.0f + __expf(-x));
}
__device__ __forceinline__ float tanh_fast(float x) {
    return 1.0f - 2.0f * __builtin_amdgcn_rcpf(__expf(2.0f * x) + 1.0f);
}
__device__ __forceinline__ float sigmoid_fast(float x) {
    return __builtin_amdgcn_rcpf(1.0f + __expf(-x));
}
__device__ __forceinline__ unsigned int cvt_pk_bf16(float lo, float hi) {
    unsigned int r;
    asm("v_cvt_pk_bf16_f32 %0, %1, %2" : "=v"(r) : "v"(lo), "v"(hi));
    return r;
}
__device__ __forceinline__ unsigned short f2bf(float x) {
    union { float f; unsigned int u; } c; c.f = x;
    unsigned int r = c.u + 0x7FFFu + ((c.u >> 16) & 1u);
    return (unsigned short)(r >> 16);
}
__device__ __forceinline__ float bf2f(unsigned short h) {
    union { unsigned int u; float f; } c; c.u = ((unsigned int)h) << 16; return c.f;
}

__global__ __launch_bounds__(256) void init_kernel(const float* __restrict__ pos,
                                                   float* __restrict__ out,
                                                   int* __restrict__ cnt)
{
    int idx = blockIdx.x * 256 + threadIdx.x;
    if (idx < OUT_TOTAL) out[idx] = (idx < 120000) ? pos[idx] : 0.0f;
    if (idx < NN) cnt[idx] = 0;
}

// ---------------- fused prep: nf->bf16, receiver hist, weight fragments ----------------
__global__ __launch_bounds__(256) void prep_all(
    const float* __restrict__ nf, unsigned short* __restrict__ nfb,
    const int* __restrict__ rcv, int* __restrict__ cnt,
    const float* __restrict__ We0, const float* __restrict__ be0,
    const float* __restrict__ We1,
    const float* __restrict__ Wx0, const float* __restrict__ Wx1,
    const float* __restrict__ Wy0, const float* __restrict__ Wy1,
    const float* __restrict__ Wh0, const float* __restrict__ Wh1,
    const float* __restrict__ Wh2,
    const float* __restrict__ Wxf, const float* __restrict__ Wyf,
    unsigned short* __restrict__ wsW)
{
    int tid = blockIdx.x * 256 + threadIdx.x;
    // nf conversion
    int i = tid * 8;
    if (i < NN * 128) {
        float4 a = *(const float4*)(nf + i);
        float4 b = *(const float4*)(nf + i + 4);
        uint4 pk;
        pk.x = cvt_pk_bf16(a.x, a.y);
        pk.y = cvt_pk_bf16(a.z, a.w);
        pk.z = cvt_pk_bf16(b.x, b.y);
        pk.w = cvt_pk_bf16(b.z, b.w);
        *(uint4*)(nfb + i) = pk;
    }
    // receiver histogram (cnt zeroed by init_kernel, stream-ordered)
    int e = tid * 2;
    if (e < EE) {
        atomicAdd(cnt + rcv[e], 1);
        atomicAdd(cnt + rcv[e + 1], 1);
    }
    // weight fragments
    if (tid >= 23552) return;
    if (tid >= 23040) {
        const float* Wf = (tid < 23296) ? Wxf : Wyf;
        unsigned short* dst = wsW + ((tid < 23296) ? WS_WXF : WS_WYF);
        int rel = tid - ((tid < 23296) ? 23040 : 23296);
        int kc = rel >> 6, lane = rel & 63;
        int lhi = lane >> 4, llo = lane & 15;
        unsigned short* o = dst + ((kc * 64 + lane) << 3);
#pragma unroll
        for (int j = 0; j < 8; ++j) {
            int k = kc * 32 + lhi * 8 + j;
            o[j] = (llo < 4) ? f2bf(Wf[k * 4 + llo]) : (unsigned short)0;
        }
        return;
    }
    const float* W; unsigned short* dst; int Kact = 128, rel; int isWe0 = 0;
    if (tid < 4608)        { W = We0; dst = wsW + WS_WE0; Kact = 264; rel = tid; isWe0 = 1; }
    else if (tid < 14848)  {
        int r = tid - 4608; int m = r >> 11; rel = r & 2047;
        switch (m) {
            case 0: W = We1; dst = wsW + WS_WE1; break;
            case 1: W = Wx0; dst = wsW + WS_WX0; break;
            case 2: W = Wx1; dst = wsW + WS_WX1; break;
            case 3: W = Wy0; dst = wsW + WS_WY0; break;
            default: W = Wy1; dst = wsW + WS_WY1; break;
        }
    }
    else if (tid < 18944)  { W = Wh0; dst = wsW + WS_WH0; Kact = 256; rel = tid - 14848; }
    else if (tid < 20992)  { W = Wh1; dst = wsW + WS_WH1; rel = tid - 18944; }
    else                   { W = Wh2; dst = wsW + WS_WH2; rel = tid - 20992; }
    int lane = rel & 63, oc = (rel >> 6) & 7, kc = rel >> 9;
    int k0 = kc * 32 + ((lane >> 4) << 3);
    int col = oc * 16 + (lane & 15);
    unsigned short* o = dst + (((kc * 8 + oc) * 64 + lane) << 3);
#pragma unroll
    for (int j = 0; j < 8; ++j) {
        int k = k0 + j;
        unsigned short v = 0;
        if (k < Kact) v = f2bf(W[k * 128 + col]);
        else if (isWe0 && k == 264) v = f2bf(be0[col]);   // bias folded at k=264 (ef col = 1)
        o[j] = v;
    }
}

// two-level scan: 1024 threads, wave shuffle scan + wave-sum scan
__global__ __launch_bounds__(1024) void scan_kernel(const int* __restrict__ cnt,
                                                    int* __restrict__ cursor)
{
    __shared__ int wsum[16];
    int t = threadIdx.x;
    int lane = t & 63, wid = t >> 6;
    int base = t * 10;
    int c[10];
    int s = 0;
#pragma unroll
    for (int i = 0; i < 10; ++i) {
        int b = base + i;
        c[i] = (b < NN) ? cnt[b] : 0;
        s += c[i];
    }
    int run = s;
#pragma unroll
    for (int off = 1; off < 64; off <<= 1) {
        int v = __shfl_up(run, off);
        if (lane >= off) run += v;
    }
    if (lane == 63) wsum[wid] = run;
    __syncthreads();
    if (t < 16) {
        int v = wsum[t];
#pragma unroll
        for (int off = 1; off < 16; off <<= 1) {
            int u = __shfl_up(v, off);
            if (t >= off) v += u;
        }
        wsum[t] = v;   // inclusive wave sums
    }
    __syncthreads();
    int wave_excl = (wid == 0) ? 0 : wsum[wid - 1];
    int excl = wave_excl + run - s;
#pragma unroll
    for (int i = 0; i < 10; ++i) {
        int b = base + i;
        if (b < NN) { cursor[b] = excl; excl += c[i]; }
    }
}

__global__ __launch_bounds__(256) void scatter_sort_kernel(const int* __restrict__ rcv,
                                                           int* __restrict__ cursor,
                                                           int* __restrict__ sortedIdx)
{
    int e = blockIdx.x * 256 + threadIdx.x;
    if (e < EE) {
        int slot = atomicAdd(cursor + rcv[e], 1);
        sortedIdx[slot] = e;
    }
}

// generic GEMM core: acc[MT][NT] += W-frag (A) x LDS activations (B)
template<int KC, int MT, int NT>
__device__ __forceinline__ void gemm_lds(const unsigned short* __restrict__ fragW,
                                         const unsigned short* Bld, const int bstride,
                                         const int tile0, const int lane,
                                         f4acc acc[MT][NT])
{
    const int lhi = lane >> 4, llo = lane & 15;
#pragma unroll
    for (int kc = 0; kc < KC; ++kc) {
        bfrag b[NT];
#pragma unroll
        for (int nt = 0; nt < NT; ++nt)
            b[nt] = *(const bfrag*)(Bld + (nt * 16 + llo) * bstride + kc * 32 + lhi * 8);
#pragma unroll
        for (int i = 0; i < MT; ++i) {
            bfrag a = *(const bfrag*)(fragW + (((kc * 8 + tile0 + i) * 64 + lane) << 3));
#pragma unroll
            for (int nt = 0; nt < NT; ++nt)
                acc[i][nt] = __builtin_amdgcn_mfma_f32_16x16x32_bf16(a, b[nt], acc[i][nt], 0, 0, 0);
        }
    }
}

template<int NT>
__device__ __forceinline__ void epilogue_silu_t(f4acc acc[2][NT], const float* __restrict__ bias,
                                                unsigned short* Dld, int lane, int w)
{
    const int lhi = lane >> 4, llo = lane & 15;
#pragma unroll
    for (int i = 0; i < 2; ++i) {
        int ch = (w * 2 + i) * 16 + lhi * 4;
        float4 bv = *(const float4*)(bias + ch);
#pragma unroll
        for (int nt = 0; nt < NT; ++nt) {
            uint2 pk;
            pk.x = cvt_pk_bf16(siluf(acc[i][nt][0] + bv.x), siluf(acc[i][nt][1] + bv.y));
            pk.y = cvt_pk_bf16(siluf(acc[i][nt][2] + bv.z), siluf(acc[i][nt][3] + bv.w));
            *(uint2*)(Dld + (nt * 16 + llo) * 136 + ch) = pk;
        }
    }
}

__device__ __forceinline__ void epilogue_silu_nobias(f4acc acc[2][2],
                                                     unsigned short* Dld, int lane, int w)
{
    const int lhi = lane >> 4, llo = lane & 15;
#pragma unroll
    for (int i = 0; i < 2; ++i) {
        int ch = (w * 2 + i) * 16 + lhi * 4;
#pragma unroll
        for (int nt = 0; nt < 2; ++nt) {
            uint2 pk;
            pk.x = cvt_pk_bf16(siluf(acc[i][nt][0]), siluf(acc[i][nt][1]));
            pk.y = cvt_pk_bf16(siluf(acc[i][nt][2]), siluf(acc[i][nt][3]));
            *(uint2*)(Dld + (nt * 16 + llo) * 136 + ch) = pk;
        }
    }
}

__global__ __launch_bounds__(256, 6) void edge_kernel(
    const float* __restrict__ pos, const float* __restrict__ vec,
    const unsigned short* __restrict__ nfb,
    const int* __restrict__ snd, const int* __restrict__ rcv,
    const int* __restrict__ sortedIdx,
    const unsigned short* __restrict__ wsW,
    const float* __restrict__ be1,
    const float* __restrict__ Winf, const float* __restrict__ binf,
    const float* __restrict__ bx0, const float* __restrict__ bx1,
    const float* __restrict__ by0, const float* __restrict__ by1,
    float* outPos, float* outSkip, float* outFeat)
{
    __shared__ unsigned short L2T[TE * 40];
    __shared__ unsigned short H0[TE * 136];   // h0 -> h1 -> h2 (in-place per branch)
    __shared__ unsigned short Hm[TE * 136];   // m
    __shared__ float dstore[TE * 24];
    __shared__ float pxy[TE * 8];
    __shared__ float gateacc[TE];
    __shared__ int sidx[TE], ridx[TE];

    const int t = threadIdx.x;
    const int lane = t & 63, w = t >> 6;
    const int lhi = lane >> 4, llo = lane & 15;
    const int e_base = blockIdx.x * TE;

    // ---- phase A ----
    if (t < TE) {
        int eid = sortedIdx[e_base + t];
        int sn = snd[eid], rn = rcv[eid];
        sidx[t] = sn; ridx[t] = rn;   // ridx non-decreasing within block
#pragma unroll
        for (int tensor = 0; tensor < 2; ++tensor) {
            const float* c = tensor ? vec : pos;
#pragma unroll
            for (int v = 0; v < 4; ++v) {
                float d0 = c[rn * 12 + v * 3 + 0] - c[sn * 12 + v * 3 + 0];
                float d1 = c[rn * 12 + v * 3 + 1] - c[sn * 12 + v * 3 + 1];
                float d2 = c[rn * 12 + v * 3 + 2] - c[sn * 12 + v * 3 + 2];
                float ss = fmaf(d0, d0, fmaf(d1, d1, d2 * d2)) + 1e-8f;
                float l = sqrtf(ss);
                float inv = __builtin_amdgcn_rcpf(1.0f + l);
                L2T[t * 40 + tensor * 4 + v] = f2bf(ss);
                dstore[t * 24 + tensor * 12 + v * 3 + 0] = d0 * inv;
                dstore[t * 24 + tensor * 12 + v * 3 + 1] = d1 * inv;
                dstore[t * 24 + tensor * 12 + v * 3 + 2] = d2 * inv;
            }
        }
#pragma unroll
        for (int j = 0; j < 6; ++j)
            *(uint2*)(L2T + t * 40 + 8 + j * 4) = make_uint2(0u, 0u);
        L2T[t * 40 + 8] = 0x3F80u;    // ef col k=264 = 1.0 (bias column, pairs with be0 row)
    }
    if (t >= 64 && t < 96) gateacc[t - 64] = 0.0f;
    __syncthreads();

    // ---- phase B: h0 = silu(ef @ We0') (bias folded into k=264) ----
    {
        const int sn0 = sidx[llo], sn1 = sidx[16 + llo];
        const int rn0 = ridx[llo], rn1 = ridx[16 + llo];
        const unsigned short* s0 = nfb + sn0 * 128 + lhi * 8;
        const unsigned short* s1 = nfb + sn1 * 128 + lhi * 8;
        const unsigned short* r0 = nfb + rn0 * 128 + lhi * 8;
        const unsigned short* r1 = nfb + rn1 * 128 + lhi * 8;
        const int mt0 = w * 2;
        f4acc acc[2][2];
#pragma unroll
        for (int i = 0; i < 2; ++i) { acc[i][0] = (f4acc){0.f,0.f,0.f,0.f}; acc[i][1] = (f4acc){0.f,0.f,0.f,0.f}; }
#pragma unroll
        for (int kc = 0; kc < 8; ++kc) {
            bfrag b0 = *(const bfrag*)((kc < 4 ? s0 : r0) + (kc & 3) * 32);
            bfrag b1 = *(const bfrag*)((kc < 4 ? s1 : r1) + (kc & 3) * 32);
#pragma unroll
            for (int i = 0; i < 2; ++i) {
                bfrag a = *(const bfrag*)(wsW + WS_WE0 + (((kc * 8 + mt0 + i) * 64 + lane) << 3));
                acc[i][0] = __builtin_amdgcn_mfma_f32_16x16x32_bf16(a, b0, acc[i][0], 0, 0, 0);
                acc[i][1] = __builtin_amdgcn_mfma_f32_16x16x32_bf16(a, b1, acc[i][1], 0, 0, 0);
            }
        }
        {
            bfrag b0 = *(const bfrag*)(L2T + llo * 40 + lhi * 8);
            bfrag b1 = *(const bfrag*)(L2T + (16 + llo) * 40 + lhi * 8);
#pragma unroll
            for (int i = 0; i < 2; ++i) {
                bfrag a = *(const bfrag*)(wsW + WS_WE0 + (((8 * 8 + mt0 + i) * 64 + lane) << 3));
                acc[i][0] = __builtin_amdgcn_mfma_f32_16x16x32_bf16(a, b0, acc[i][0], 0, 0, 0);
                acc[i][1] = __builtin_amdgcn_mfma_f32_16x16x32_bf16(a, b1, acc[i][1], 0, 0, 0);
            }
        }
        epilogue_silu_nobias(acc, H0, lane, w);
    }
    __syncthreads();

    // ---- phase C: m + gate fused ----
    {
        f4acc acc[2][2];
#pragma unroll
        for (int i = 0; i < 2; ++i) { acc[i][0] = (f4acc){0.f,0.f,0.f,0.f}; acc[i][1] = (f4acc){0.f,0.f,0.f,0.f}; }
        gemm_lds<4, 2, 2>(wsW + WS_WE1, H0, 136, w * 2, lane, acc);
        float gp0 = 0.0f, gp1 = 0.0f;
#pragma unroll
        for (int i = 0; i < 2; ++i) {
            int ch = (w * 2 + i) * 16 + lhi * 4;
            float4 bv = *(const float4*)(be1 + ch);
            float4 wg = *(const float4*)(Winf + ch);
#pragma unroll
            for (int nt = 0; nt < 2; ++nt) {
                float v0 = siluf(acc[i][nt][0] + bv.x);
                float v1 = siluf(acc[i][nt][1] + bv.y);
                float v2 = siluf(acc[i][nt][2] + bv.z);
                float v3 = siluf(acc[i][nt][3] + bv.w);
                uint2 pk;
                pk.x = cvt_pk_bf16(v0, v1);
                pk.y = cvt_pk_bf16(v2, v3);
                *(uint2*)(Hm + (nt * 16 + llo) * 136 + ch) = pk;
                float g = fmaf(v0, wg.x, fmaf(v1, wg.y, fmaf(v2, wg.z, v3 * wg.w)));
                if (nt == 0) gp0 += g; else gp1 += g;
            }
        }
        gp0 += __shfl_xor(gp0, 16); gp0 += __shfl_xor(gp0, 32);
        gp1 += __shfl_xor(gp1, 16); gp1 += __shfl_xor(gp1, 32);
        if (lane < 16) {
            atomicAdd(&gateacc[lane], gp0);
            atomicAdd(&gateacc[16 + lane], gp1);
        }
    }
    __syncthreads();

    // ---- branches x,y: h1 -> h2 (in-place H0) -> head via MFMA ----
#pragma unroll 1
    for (int br = 0; br < 2; ++br) {
        {   // D: h1 = silu(m @ W0 + b0) -> H0
            const unsigned short* fw = wsW + (br ? WS_WY0 : WS_WX0);
            const float* bias = br ? by0 : bx0;
            f4acc acc[2][2];
#pragma unroll
            for (int i = 0; i < 2; ++i) { acc[i][0] = (f4acc){0.f,0.f,0.f,0.f}; acc[i][1] = (f4acc){0.f,0.f,0.f,0.f}; }
            gemm_lds<4, 2, 2>(fw, Hm, 136, w * 2, lane, acc);
            epilogue_silu_t<2>(acc, bias, H0, lane, w);
        }
        __syncthreads();
        {   // E: h2 = silu(h1 @ W1 + b1) -> H0 in-place (barrier between read and write)
            const unsigned short* fw = wsW + (br ? WS_WY1 : WS_WX1);
            const float* bias = br ? by1 : bx1;
            f4acc acc[2][2];
#pragma unroll
            for (int i = 0; i < 2; ++i) { acc[i][0] = (f4acc){0.f,0.f,0.f,0.f}; acc[i][1] = (f4acc){0.f,0.f,0.f,0.f}; }
            gemm_lds<4, 2, 2>(fw, H0, 136, w * 2, lane, acc);
            __syncthreads();
            epilogue_silu_t<2>(acc, bias, H0, lane, w);
        }
        __syncthreads();
        // head: p = h2 @ Wf via one MFMA tile (waves 0,1 handle nt = w)
        if (w < 2) {
            const unsigned short* fw = wsW + (br ? WS_WYF : WS_WXF);
            f4acc h = (f4acc){0.f, 0.f, 0.f, 0.f};
#pragma unroll
            for (int kc = 0; kc < 4; ++kc) {
                bfrag b = *(const bfrag*)(H0 + (w * 16 + llo) * 136 + kc * 32 + lhi * 8);
                bfrag a = *(const bfrag*)(fw + ((kc * 64 + lane) << 3));
                h = __builtin_amdgcn_mfma_f32_16x16x32_bf16(a, b, h, 0, 0, 0);
            }
            if (lhi == 0) {
#pragma unroll
                for (int v = 0; v < 4; ++v)
                    pxy[(w * 16 + llo) * 8 + br * 4 + v] = h[v];
            }
        }
        __syncthreads();
    }

    // ---- finalize heads + gate ----
    pxy[t] = tanh_fast(pxy[t]) * INV_AVG;
    if (t < TE) gateacc[t] = sigmoid_fast(gateacc[t] + binf[0]) * INV_AVG;
    __syncthreads();

    // ---- merged scatter (sorted receivers) ----
    // features: waves 0-1, 2 halves x 64 channel-pairs; 16-edge runs
    if (t < 128) {
        int half = t >> 6, pair = t & 63;
        int jj = pair * 2;
        int e0h = half * 16;
        float a0 = 0.0f, a1 = 0.0f;
        int prev_r = ridx[e0h];
#pragma unroll
        for (int i = 0; i < 16; ++i) {
            int e = e0h + i;
            int r = ridx[e];
            if (r != prev_r) {
                atomicAdd(outFeat + prev_r * 128 + jj, a0);
                atomicAdd(outFeat + prev_r * 128 + jj + 1, a1);
                a0 = a1 = 0.0f;
                prev_r = r;
            }
            unsigned int pk = *(const unsigned int*)(Hm + e * 136 + jj);
            float g = gateacc[e];
            a0 = fmaf(bf2f((unsigned short)(pk & 0xffffu)), g, a0);
            a1 = fmaf(bf2f((unsigned short)(pk >> 16)), g, a1);
        }
        atomicAdd(outFeat + prev_r * 128 + jj, a0);
        atomicAdd(outFeat + prev_r * 128 + jj + 1, a1);
    } else if (t >= 208) {
        // shifts: wave 3 upper half, 24 comps x 2 halves
        int s = t - 208;
        int c = s >> 1, half = s & 1;
        int tensor = (c >= 12) ? 1 : 0;
        int rem = c - tensor * 12;
        int v = rem / 3;
        float* dstp = tensor ? outSkip : outPos;
        int e0h = half * 16;
        float acc = 0.0f;
        int prev_r = ridx[e0h];
#pragma unroll
        for (int i = 0; i < 16; ++i) {
            int e = e0h + i;
            int r = ridx[e];
            if (r != prev_r) {
                atomicAdd(dstp + prev_r * 12 + rem, acc);
                acc = 0.0f;
                prev_r = r;
            }
            acc = fmaf(dstore[e * 24 + c], pxy[e * 8 + tensor * 4 + v], acc);
        }
        atomicAdd(dstp + prev_r * 12 + rem, acc);
    }
}

// ---------------- node kernel: MFMA phi_h, 16 nodes/block ----------------
__global__ __launch_bounds__(256) void node_kernel(
    const float* __restrict__ nf, const unsigned short* __restrict__ nfb,
    const float* __restrict__ nvec,
    const unsigned short* __restrict__ wsW,
    const float* __restrict__ bh0, const float* __restrict__ bh1,
    const float* __restrict__ bh2,
    float* outFeat /* holds m_i on entry */, float* outVec,
    const float* __restrict__ outSkip)
{
    __shared__ unsigned short A[TN * 264];   // hin bf16 [16][256] stride 264
    __shared__ unsigned short H1[TN * 136];
    __shared__ unsigned short H2b[TN * 136];
    const int t = threadIdx.x;
    const int lane = t & 63, w = t >> 6;
    const int lhi = lane >> 4, llo = lane & 15;
    const int n_base = blockIdx.x * TN;

    // gather m_i (fp32 -> bf16): 16 rows x 64 channel-pairs = 1024 tasks
#pragma unroll
    for (int it = 0; it < 4; ++it) {
        int idx = t + it * 256;
        int row = idx >> 6, q = idx & 63;
        int n = n_base + row;
        float2 v = make_float2(0.f, 0.f);
        if (n < NN) v = *(const float2*)(outFeat + n * 128 + q * 2);
        *(unsigned int*)(A + row * 264 + q * 2) = cvt_pk_bf16(v.x, v.y);
    }
    // copy nf (already bf16 in nfb): 16 rows x 16 b128 = 256 tasks
    {
        int row = t >> 4, q = t & 15;
        int n = n_base + row;
        uint4 v = make_uint4(0u, 0u, 0u, 0u);
        if (n < NN) v = *(const uint4*)(nfb + n * 128 + q * 8);
        *(uint4*)(A + row * 264 + 128 + q * 8) = v;
    }
    __syncthreads();
    {   // L1: h1 = silu(hin @ Wh0 + bh0), K=256
        f4acc acc[2][1];
        acc[0][0] = (f4acc){0.f,0.f,0.f,0.f}; acc[1][0] = (f4acc){0.f,0.f,0.f,0.f};
        gemm_lds<8, 2, 1>(wsW + WS_WH0, A, 264, w * 2, lane, acc);
        epilogue_silu_t<1>(acc, bh0, H1, lane, w);
    }
    __syncthreads();
    {   // L2
        f4acc acc[2][1];
        acc[0][0] = (f4acc){0.f,0.f,0.f,0.f}; acc[1][0] = (f4acc){0.f,0.f,0.f,0.f};
        gemm_lds<4, 2, 1>(wsW + WS_WH1, H1, 136, w * 2, lane, acc);
        epilogue_silu_t<1>(acc, bh1, H2b, lane, w);
    }
    __syncthreads();
    {   // L3: out = h2 @ Wh2 + bh2 + nf (residual), fp32 global store
        f4acc acc[2][1];
        acc[0][0] = (f4acc){0.f,0.f,0.f,0.f}; acc[1][0] = (f4acc){0.f,0.f,0.f,0.f};
        gemm_lds<4, 2, 1>(wsW + WS_WH2, H2b, 136, w * 2, lane, acc);
#pragma unroll
        for (int i = 0; i < 2; ++i) {
            int ch = (w * 2 + i) * 16 + lhi * 4;
            float4 bv = *(const float4*)(bh2 + ch);
            int n = n_base + llo;
            if (n < NN) {
                float4 r = *(const float4*)(nf + n * 128 + ch);
                float4 o;
                o.x = acc[i][0][0] + bv.x + r.x;
                o.y = acc[i][0][1] + bv.y + r.y;
                o.z = acc[i][0][2] + bv.z + r.z;
                o.w = acc[i][0][3] + bv.w + r.w;
                *(float4*)(outFeat + n * 128 + ch) = o;
            }
        }
    }
    // vectors_out = skip + node_vectors : 16 nodes x 12 = 192
    if (t < TN * 12) {
        int n = n_base + t / 12;
        if (n < NN) {
            int g = n_base * 12 + t;
            outVec[g] = outSkip[g] + nvec[g];
        }
    }
}

extern "C" void kernel_launch(void* const* d_in, const int* in_sizes, int n_in,
                              void* d_out, int out_size, void* d_ws, size_t ws_size,
                              hipStream_t stream)
{
    (void)in_sizes; (void)n_in; (void)out_size; (void)ws_size;

    const float* pos  = (const float*)d_in[0];
    const float* vecv = (const float*)d_in[1];
    const float* nf   = (const float*)d_in[2];
    const int*   snd  = (const int*)d_in[3];
    const int*   rcv  = (const int*)d_in[4];
    const float* We0  = (const float*)d_in[5];
    const float* be0  = (const float*)d_in[6];
    const float* We1  = (const float*)d_in[7];
    const float* be1  = (const float*)d_in[8];
    const float* Winf = (const float*)d_in[9];
    const float* binf = (const float*)d_in[10];
    const float* Wx0  = (const float*)d_in[11];
    const float* bx0  = (const float*)d_in[12];
    const float* Wx1  = (const float*)d_in[13];
    const float* bx1  = (const float*)d_in[14];
    const float* Wxf  = (const float*)d_in[15];
    const float* Wy0  = (const float*)d_in[16];
    const float* by0  = (const float*)d_in[17];
    const float* Wy1  = (const float*)d_in[18];
    const float* by1  = (const float*)d_in[19];
    const float* Wyf  = (const float*)d_in[20];
    const float* Wh0  = (const float*)d_in[21];
    const float* bh0  = (const float*)d_in[22];
    const float* Wh1  = (const float*)d_in[23];
    const float* bh1  = (const float*)d_in[24];
    const float* Wh2  = (const float*)d_in[25];
    const float* bh2  = (const float*)d_in[26];

    float* out     = (float*)d_out;
    float* outPos  = out + OUT_POS;
    float* outVec  = out + OUT_VEC;
    float* outFeat = out + OUT_FEAT;
    float* outSkip = out + OUT_SKIP;

    char* ws = (char*)d_ws;
    unsigned short* wsW = (unsigned short*)ws;
    unsigned short* nfb = (unsigned short*)(ws + WS_OFF_NF);
    int* sortedIdx      = (int*)(ws + WS_OFF_SORT);
    int* cnt            = (int*)(ws + WS_OFF_CNT);
    int* cursor         = (int*)(ws + WS_OFF_CUR);

    init_kernel<<<(OUT_TOTAL + 255) / 256, 256, 0, stream>>>(pos, out, cnt);

    prep_all<<<(NN * 128 / 8 + 255) / 256, 256, 0, stream>>>(
        nf, nfb, rcv, cnt,
        We0, be0, We1, Wx0, Wx1, Wy0, Wy1, Wh0, Wh1, Wh2, Wxf, Wyf, wsW);

    scan_kernel<<<1, 1024, 0, stream>>>(cnt, cursor);
    scatter_sort_kernel<<<(EE + 255) / 256, 256, 0, stream>>>(rcv, cursor, sortedIdx);

    edge_kernel<<<EE / TE, 256, 0, stream>>>(
        pos, vecv, nfb, snd, rcv, sortedIdx, wsW,
        be1, Winf, binf,
        bx0, bx1, by0, by1,
        outPos, outSkip, outFeat);

    node_kernel<<<(NN + TN - 1) / TN, 256, 0, stream>>>(
        nf, nfb, vecv, wsW, bh0, bh1, bh2,
        outFeat, outVec, outSkip);
}